// Round 4
// baseline (3549.886 us; speedup 1.0000x reference)
//
#include <hip/hip_runtime.h>

typedef _Float16 f16;
typedef _Float16 f16x8 __attribute__((ext_vector_type(8)));
typedef float f32x4 __attribute__((ext_vector_type(4)));
typedef float f32x16 __attribute__((ext_vector_type(16)));
typedef unsigned int u32;
typedef u32 u32x4 __attribute__((ext_vector_type(4)));

#define SEQ 512
#define BATCH 256
#define DIN 512
#define DH 1024
#define DK 1536
#define NCLS 1000

#define NGROUP 8      // batch groups (XCD round-robin by blockIdx&7; perf heuristic only)
#define WGPG 32       // workgroups per group
#define ROWS 32       // batch rows per group
#define OUTS 32       // hidden outputs per WG
#define KSLICES 96    // DK/16
#define RED_STRIDE 33

// ws layout
#define WF_BYTES    ((size_t)DH * DK * 2)          // 3 MB  W in f16 frag layout
#define HBUF_OFF    WF_BYTES
#define HBUF_HALF   ((size_t)BATCH * DH * 2)       // 512 KB per buffer
#define HBUF_BYTES  (2 * HBUF_HALF)
#define CNT_OFF     (HBUF_OFF + HBUF_BYTES)
#define CNT_BYTES   (NGROUP * 512)                 // 8 counters, 512B apart

// ---- L3-coherent (bypass L1+L2) access helpers: sc0 sc1 ----
__device__ __forceinline__ u32 cnt_load(const u32* p) {
    u32 v;
    asm volatile("global_load_dword %0, %1, off sc0 sc1\n\ts_waitcnt vmcnt(0)"
                 : "=v"(v) : "v"(p) : "memory");
    return v;
}
__device__ __forceinline__ void cnt_add(u32* p) {
    u32 one = 1;
    asm volatile("global_atomic_add %0, %1, off sc1" :: "v"(p), "v"(one) : "memory");
}
__device__ __forceinline__ u32x4 hload4(const void* p) {
    u32x4 v;
    asm volatile("global_load_dwordx4 %0, %1, off sc0 sc1" : "=v"(v) : "v"(p) : "memory");
    return v;
}
__device__ __forceinline__ void hstore8(void* p, uint2 v) {
    asm volatile("global_store_dwordx2 %0, %1, off sc0 sc1" :: "v"(p), "v"(v) : "memory");
}

// ---- W [1024][1536] fp32 -> f16 A-fragment-linear layout ----
// Wf[((s*96 + j)*64 + lane)*8 + v] = W[s*32 + (lane&31)][j*16 + (lane>>5)*8 + v]
__global__ void __launch_bounds__(256) convert_W_kernel(const float* __restrict__ W,
                                                        f16* __restrict__ Wf) {
    int id = blockIdx.x * 256 + threadIdx.x;
    if (id >= DH * DK) return;
    int v = id & 7;
    int l = (id >> 3) & 63;
    int rest = id >> 9;            // s*96 + j
    int j = rest % KSLICES;
    int s = rest / KSLICES;
    int row = s * OUTS + (l & 31);
    int k = j * 16 + ((l >> 5) << 3) + v;
    Wf[id] = (f16)W[row * DK + k];
}

// ---- persistent RNN kernel: 256 WGs (8 groups x 32), 256 threads each ----
// Wave w owns K-slices j with j%4==w: 8 x-slices (j<32) + 16 h-slices (j>=32).
// Sync: per-group cumulative atomic counter in L3; h data via L3 (sc0 sc1).
__global__ void __launch_bounds__(256, 1) rnn_kernel(const float* __restrict__ x,
                                                     const float* __restrict__ bias,
                                                     const f16* __restrict__ Wf,
                                                     f16* __restrict__ hbuf,
                                                     u32* __restrict__ cnt) {
    __shared__ float red[4 * OUTS * RED_STRIDE];
    __shared__ float blds[OUTS];

    const int tid  = threadIdx.x;
    const int g    = blockIdx.x & 7;   // group
    const int s    = blockIdx.x >> 3;  // out-slice 0..31
    const int wave = tid >> 6;
    const int lane = tid & 63;
    const int r    = lane & 31;        // batch row within group / MFMA B col
    const int hi   = lane >> 5;        // K-half within slice

    if (tid < OUTS) blds[tid] = bias[s * OUTS + tid];

    // weight A-fragments -> registers
    f16x8 wf[24];
    {
        const f16x8* wp = ((const f16x8*)Wf) + (size_t)s * KSLICES * 64 + lane;
#pragma unroll
        for (int i = 0; i < 24; ++i) wf[i] = wp[(size_t)(wave + 4 * i) * 64];
    }

    u32* gcnt = cnt + g * 128;   // 512B spacing

    // finish-phase assignment: thread = (batch row b_, 4-output chunk o0)
    const int b_ = tid >> 3;
    const int o0 = (tid & 7) * 4;

    for (int t = 0; t < SEQ; ++t) {
        f32x16 acc = {0,0,0,0, 0,0,0,0, 0,0,0,0, 0,0,0,0};

        // ---- 1. x-part (independent of h; overlap window for stragglers) ----
        {
            const float* xrow = x + ((size_t)t * BATCH + g * ROWS + r) * DIN + hi * 8;
#pragma unroll
            for (int i = 0; i < 8; ++i) {
                const float* xp = xrow + (wave + 4 * i) * 16;
                f32x4 a0 = *(const f32x4*)xp;
                f32x4 a1 = *(const f32x4*)(xp + 4);
                f16x8 bf;
                bf[0] = (f16)a0[0]; bf[1] = (f16)a0[1]; bf[2] = (f16)a0[2]; bf[3] = (f16)a0[3];
                bf[4] = (f16)a1[0]; bf[5] = (f16)a1[1]; bf[6] = (f16)a1[2]; bf[7] = (f16)a1[3];
                acc = __builtin_amdgcn_mfma_f32_32x32x16_f16(wf[i], bf, acc, 0, 0, 0);
            }
        }

        // ---- 2. wait: group's step t-1 complete (1 broadcast load/wave/iter) ----
        {
            const u32 need = (u32)(WGPG * t);
            u32 v = cnt_load(gcnt);
            while (v < need) {
                __builtin_amdgcn_s_sleep(1);
                v = cnt_load(gcnt);
            }
        }

        // ---- 3. h-part: single untagged sweep from L3, then MFMA ----
        {
            const char* hrb = (const char*)(hbuf + ((size_t)(t & 1) * BATCH + g * ROWS + r) * DH
                                            + hi * 8) + wave * 32;
            u32x4 hv[16];
#pragma unroll
            for (int i = 0; i < 16; ++i) hv[i] = hload4(hrb + i * 128);
            asm volatile("s_waitcnt vmcnt(0)" ::: "memory");
            __builtin_amdgcn_sched_barrier(0);
            union cvt_t { u32x4 u; f16x8 h; };
#pragma unroll
            for (int i = 0; i < 16; ++i) {
                cvt_t c; c.u = hv[i];
                acc = __builtin_amdgcn_mfma_f32_32x32x16_f16(wf[8 + i], c.h, acc, 0, 0, 0);
            }
        }

        // ---- 4. write K-split partials (C/D: col=lane&31, row=(v&3)+8*(v>>2)+4*hi) ----
        {
            float* rw = red + wave * (OUTS * RED_STRIDE);
            int rbase = hi << 2;
#pragma unroll
            for (int v = 0; v < 16; ++v) {
                int orow = (v & 3) + 8 * (v >> 2) + rbase;
                rw[orow * RED_STRIDE + r] = acc[v];
            }
        }
        __syncthreads();

        // ---- 5. finish: reduce 4 partials + bias, fast tanh, store h to L3 ----
        {
            f16* hout = hbuf + ((size_t)((t + 1) & 1) * BATCH + g * ROWS + b_) * DH + s * OUTS + o0;
            union { f16 h4[4]; uint2 u; } uu;
#pragma unroll
            for (int i = 0; i < 4; ++i) {
                int o = o0 + i;
                float p = blds[o];
#pragma unroll
                for (int w2 = 0; w2 < 4; ++w2)
                    p += red[w2 * (OUTS * RED_STRIDE) + o * RED_STRIDE + b_];
                // tanh(p) = 1 - 2/(e^{2p}+1)
                float e = __expf(2.f * p);
                uu.h4[i] = (f16)(1.f - 2.f / (e + 1.f));
            }
            hstore8(hout, uu.u);
        }
        // __syncthreads drains vmcnt(0) => all this WG's h stores are in L3;
        // also protects red[] for the next iteration.
        __syncthreads();
        if (tid == 0) cnt_add(gcnt);   // fire-and-forget L3 atomic
    }
}

// ---- classify: block per class, thread per batch row ----
__global__ void __launch_bounds__(256) classify_kernel(const f16* __restrict__ h,
                                                       const float* __restrict__ Wc,
                                                       const float* __restrict__ bc,
                                                       float* __restrict__ out) {
    __shared__ float wrow[DH];
    int c = blockIdx.x;
    int tid = threadIdx.x;
    for (int i = tid; i < DH; i += 256) wrow[i] = Wc[(size_t)c * DH + i];
    __syncthreads();
    const f16* hrow = h + (size_t)tid * DH;
    float acc = bc[c];
#pragma unroll 4
    for (int k = 0; k < DH; k += 8) {
        f16x8 hv = *(const f16x8*)(hrow + k);
#pragma unroll
        for (int i2 = 0; i2 < 8; ++i2) acc += (float)hv[i2] * wrow[k + i2];
    }
    out[(size_t)tid * NCLS + c] = acc;
}

extern "C" void kernel_launch(void* const* d_in, const int* in_sizes, int n_in,
                              void* d_out, int out_size, void* d_ws, size_t ws_size,
                              hipStream_t stream) {
    const float* x  = (const float*)d_in[0];
    const float* W  = (const float*)d_in[1];
    const float* b  = (const float*)d_in[2];
    const float* Wc = (const float*)d_in[3];
    const float* bc = (const float*)d_in[4];
    float* out = (float*)d_out;

    char* ws = (char*)d_ws;
    f16* Wf   = (f16*)ws;
    f16* hbuf = (f16*)(ws + HBUF_OFF);
    u32* cnt  = (u32*)(ws + CNT_OFF);

    // h0 = 0 (buffer 0); counters cumulative from 0 — reset every call so
    // graph replays are deterministic.
    hipMemsetAsync(hbuf, 0, HBUF_BYTES, stream);
    hipMemsetAsync(cnt, 0, CNT_BYTES, stream);

    convert_W_kernel<<<(DH * DK + 255) / 256, 256, 0, stream>>>(W, Wf);

    void* args[5];
    args[0] = (void*)&x;
    args[1] = (void*)&b;
    args[2] = (void*)&Wf;
    args[3] = (void*)&hbuf;
    args[4] = (void*)&cnt;
    hipLaunchCooperativeKernel((const void*)rnn_kernel, dim3(256), dim3(256),
                               args, 0, stream);

    // final h is in hbuf[0] (step 511 writes buffer (512)&1 = 0)
    classify_kernel<<<dim3(NCLS), dim3(256), 0, stream>>>(hbuf, Wc, bc, out);
}

// Round 5
// 2505.474 us; speedup vs baseline: 1.4169x; 1.4169x over previous
//
#include <hip/hip_runtime.h>

typedef _Float16 f16;
typedef _Float16 f16x8 __attribute__((ext_vector_type(8)));
typedef float f32x4 __attribute__((ext_vector_type(4)));
typedef float f32x16 __attribute__((ext_vector_type(16)));
typedef unsigned int u32;
typedef u32 u32x4 __attribute__((ext_vector_type(4)));

#define SEQ 512
#define BATCH 256
#define DIN 512
#define DH 1024
#define DK 1536
#define NCLS 1000

#define NGROUP 8      // groups == physical XCDs (dynamic via HW_REG_XCC_ID)
#define WGPG 32       // workgroups per group (guaranteed by 1-WG/CU pigeonhole)
#define ROWS 32       // batch rows per group
#define OUTS 32       // hidden outputs per WG
#define KSLICES 96    // DK/16
#define RED_STRIDE 33

// dynamic LDS request: 96 KB forces max 1 WG/CU (160 KB pool) -> with a
// cooperative launch of 256 WGs on 256 CUs, exactly 1 WG/CU, 32 WGs/XCD.
#define SMEM_ALLOC (96 * 1024)

// ws layout
#define WF_BYTES    ((size_t)DH * DK * 2)          // 3 MB  W in f16 frag layout
#define HBUF_OFF    WF_BYTES
#define HBUF_HALF   ((size_t)BATCH * DH * 2)       // 512 KB per buffer
#define HBUF_BYTES  (2 * HBUF_HALF)
#define SLOT_OFF    (HBUF_OFF + HBUF_BYTES)
#define SLOT_BYTES  (NGROUP * 64)                  // 8 slot counters, 64B apart

// tag bit: f16 bit14 (0x4000). tanh output |h|<=1 -> bit14 always 0 in real data.
#define TAGBITS 0x40004000u
#define STRIPM  0xBFFFBFFFu

// ---- XCD-local L2-scope access: sc0 = bypass L1, coherence point = XCD L2 ----
__device__ __forceinline__ u32x4 hload4(const void* p) {
    u32x4 v;
    asm volatile("global_load_dwordx4 %0, %1, off sc0" : "=v"(v) : "v"(p) : "memory");
    return v;
}
__device__ __forceinline__ void hstore8(void* p, uint2 v) {
    asm volatile("global_store_dwordx2 %0, %1, off sc0" :: "v"(p), "v"(v) : "memory");
}

// ---- W [1024][1536] fp32 -> f16 A-fragment-linear layout ----
// Wf[((s*96 + j)*64 + lane)*8 + v] = W[s*32 + (lane&31)][j*16 + (lane>>5)*8 + v]
__global__ void __launch_bounds__(256) convert_W_kernel(const float* __restrict__ W,
                                                        f16* __restrict__ Wf) {
    int id = blockIdx.x * 256 + threadIdx.x;
    if (id >= DH * DK) return;
    int v = id & 7;
    int l = (id >> 3) & 63;
    int rest = id >> 9;            // s*96 + j
    int j = rest % KSLICES;
    int s = rest / KSLICES;
    int row = s * OUTS + (l & 31);
    int k = j * 16 + ((l >> 5) << 3) + v;
    Wf[id] = (f16)W[row * DK + k];
}

// ---- persistent RNN kernel: 256 WGs, dynamically grouped by physical XCD ----
// WG (g=XCC_ID, s=slot): batch rows g*32..+31, hidden outputs s*32..+31.
// Wave w owns K-slices j%4==w: 8 x-slices (j<32) + 16 h-slices (j>=32).
// h exchange: tagged data through the XCD-local L2 (sc0). No flags, no fences.
__global__ void __launch_bounds__(256, 1) rnn_kernel(const float* __restrict__ x,
                                                     const float* __restrict__ bias,
                                                     const f16* __restrict__ Wf,
                                                     f16* __restrict__ hbuf,
                                                     int* __restrict__ xslots) {
    extern __shared__ char smem[];
    float* red  = (float*)smem;                               // 16896 B
    float* blds = (float*)(smem + 4 * OUTS * RED_STRIDE * 4); // 128 B
    int*   meta = (int*)(blds + OUTS);

    const int tid  = threadIdx.x;
    const int wave = tid >> 6;
    const int lane = tid & 63;
    const int r    = lane & 31;        // batch row within group / MFMA B col
    const int hi   = lane >> 5;        // K-half within slice

    // ---- dynamic grouping: group = physical XCD, slot = arrival order ----
    if (tid == 0) {
        u32 xcc;
        asm volatile("s_getreg_b32 %0, hwreg(HW_REG_XCC_ID)" : "=s"(xcc));
        int g = (int)(xcc & 7);
        meta[0] = g;
        meta[1] = atomicAdd(&xslots[g], 1) & 31;  // device-scope; 0..31 by pigeonhole
    }
    __syncthreads();
    const int g = meta[0];
    const int s = meta[1];

    if (tid < OUTS) blds[tid] = bias[s * OUTS + tid];

    // weight A-fragments -> registers (96 VGPRs/lane)
    f16x8 wf[24];
    {
        const f16x8* wp = ((const f16x8*)Wf) + (size_t)s * KSLICES * 64 + lane;
#pragma unroll
        for (int i = 0; i < 24; ++i) wf[i] = wp[(size_t)(wave + 4 * i) * 64];
    }

    // finish-phase assignment: thread = (batch row b_, 4-output chunk o0)
    const int b_ = tid >> 3;
    const int o0 = (tid & 7) * 4;

    for (int t = 0; t < SEQ; ++t) {
        f32x16 acc = {0,0,0,0, 0,0,0,0, 0,0,0,0, 0,0,0,0};

        // ---- 1. x-part (independent of h; overlap window for stragglers) ----
        {
            const float* xrow = x + ((size_t)t * BATCH + g * ROWS + r) * DIN + hi * 8;
#pragma unroll
            for (int i = 0; i < 8; ++i) {
                const float* xp = xrow + (wave + 4 * i) * 16;
                f32x4 a0 = *(const f32x4*)xp;
                f32x4 a1 = *(const f32x4*)(xp + 4);
                f16x8 bf;
                bf[0] = (f16)a0[0]; bf[1] = (f16)a0[1]; bf[2] = (f16)a0[2]; bf[3] = (f16)a0[3];
                bf[4] = (f16)a1[0]; bf[5] = (f16)a1[1]; bf[6] = (f16)a1[2]; bf[7] = (f16)a1[3];
                acc = __builtin_amdgcn_mfma_f32_32x32x16_f16(wf[i], bf, acc, 0, 0, 0);
            }
        }

        // ---- 2. h-part: poll the tagged data itself in the local L2 ----
        {
            const char* hrb = (const char*)(hbuf + ((size_t)(t & 1) * BATCH + g * ROWS + r) * DH
                                            + hi * 8) + wave * 32;
            const u32 rtag = (u32)((t >> 1) & 1);   // expected generation tag
            u32x4 hv[16];
            if (rtag == 0) {
                for (;;) {
#pragma unroll
                    for (int i = 0; i < 16; ++i) hv[i] = hload4(hrb + i * 128);
                    asm volatile("s_waitcnt vmcnt(0)" ::: "memory");
                    u32 orr = 0;
#pragma unroll
                    for (int i = 0; i < 16; ++i) orr |= hv[i].x | hv[i].y | hv[i].z | hv[i].w;
                    if (__all((orr & TAGBITS) == 0u)) break;
                }
            } else {
                for (;;) {
#pragma unroll
                    for (int i = 0; i < 16; ++i) hv[i] = hload4(hrb + i * 128);
                    asm volatile("s_waitcnt vmcnt(0)" ::: "memory");
                    u32 andv = 0xFFFFFFFFu;
#pragma unroll
                    for (int i = 0; i < 16; ++i) andv &= hv[i].x & hv[i].y & hv[i].z & hv[i].w;
                    if (__all((andv & TAGBITS) == TAGBITS)) break;
                }
#pragma unroll
                for (int i = 0; i < 16; ++i) hv[i] &= STRIPM;   // strip tag bits
            }
            union cvt_t { u32x4 u; f16x8 h; };
#pragma unroll
            for (int i = 0; i < 16; ++i) {
                cvt_t c; c.u = hv[i];
                acc = __builtin_amdgcn_mfma_f32_32x32x16_f16(wf[8 + i], c.h, acc, 0, 0, 0);
            }
        }

        // ---- 3. write K-split partials (C/D: col=lane&31, row=(v&3)+8*(v>>2)+4*hi) ----
        {
            float* rw = red + wave * (OUTS * RED_STRIDE);
            int rbase = hi << 2;
#pragma unroll
            for (int v = 0; v < 16; ++v) {
                int orow = (v & 3) + 8 * (v >> 2) + rbase;
                rw[orow * RED_STRIDE + r] = acc[v];
            }
        }
        __syncthreads();

        // ---- 4. finish: reduce 4 partials + bias, fast tanh, tagged store ----
        {
            const u32 wtag = (u32)(((t + 1) >> 1) & 1);
            f16* hout = hbuf + ((size_t)((t + 1) & 1) * BATCH + g * ROWS + b_) * DH + s * OUTS + o0;
            union { f16 h4[4]; uint2 u; } uu;
#pragma unroll
            for (int i = 0; i < 4; ++i) {
                int o = o0 + i;
                float p = blds[o];
#pragma unroll
                for (int w2 = 0; w2 < 4; ++w2)
                    p += red[w2 * (OUTS * RED_STRIDE) + o * RED_STRIDE + b_];
                // tanh(p) = 1 - 2/(e^{2p}+1); |result| <= 1 so f16 bit14 == 0
                float e = __expf(2.f * p);
                uu.h4[i] = (f16)(1.f - 2.f / (e + 1.f));
            }
            if (wtag) { uu.u.x |= TAGBITS; uu.u.y |= TAGBITS; }
            hstore8(hout, uu.u);
        }
        __syncthreads();   // red[] safe for next step
    }
}

// ---- classify: block per class, thread per batch row ----
__global__ void __launch_bounds__(256) classify_kernel(const f16* __restrict__ h,
                                                       const float* __restrict__ Wc,
                                                       const float* __restrict__ bc,
                                                       float* __restrict__ out) {
    __shared__ float wrow[DH];
    int c = blockIdx.x;
    int tid = threadIdx.x;
    for (int i = tid; i < DH; i += 256) wrow[i] = Wc[(size_t)c * DH + i];
    __syncthreads();
    const f16* hrow = h + (size_t)tid * DH;
    float acc = bc[c];
#pragma unroll 4
    for (int k = 0; k < DH; k += 8) {
        f16x8 hv = *(const f16x8*)(hrow + k);
#pragma unroll
        for (int i2 = 0; i2 < 8; ++i2) acc += (float)hv[i2] * wrow[k + i2];
    }
    out[(size_t)tid * NCLS + c] = acc;
}

extern "C" void kernel_launch(void* const* d_in, const int* in_sizes, int n_in,
                              void* d_out, int out_size, void* d_ws, size_t ws_size,
                              hipStream_t stream) {
    const float* x  = (const float*)d_in[0];
    const float* W  = (const float*)d_in[1];
    const float* b  = (const float*)d_in[2];
    const float* Wc = (const float*)d_in[3];
    const float* bc = (const float*)d_in[4];
    float* out = (float*)d_out;

    char* ws = (char*)d_ws;
    f16* Wf     = (f16*)ws;
    f16* hbuf   = (f16*)(ws + HBUF_OFF);
    int* xslots = (int*)(ws + SLOT_OFF);

    // buffer 0: zeros = h0 (valid, tag 0).  buffer 1: 0x4040 = stale (bit14 set)
    // for the first tag-0 read at t=1.  Slot counters zeroed.  Every call.
    hipMemsetAsync(hbuf, 0, HBUF_HALF, stream);
    hipMemsetAsync((char*)hbuf + HBUF_HALF, 0x40, HBUF_HALF, stream);
    hipMemsetAsync(xslots, 0, SLOT_BYTES, stream);

    convert_W_kernel<<<(DH * DK + 255) / 256, 256, 0, stream>>>(W, Wf);

    hipFuncSetAttribute((const void*)rnn_kernel,
                        hipFuncAttributeMaxDynamicSharedMemorySize, SMEM_ALLOC);
    void* args[5];
    args[0] = (void*)&x;
    args[1] = (void*)&b;
    args[2] = (void*)&Wf;
    args[3] = (void*)&hbuf;
    args[4] = (void*)&xslots;
    hipLaunchCooperativeKernel((const void*)rnn_kernel, dim3(256), dim3(256),
                               args, SMEM_ALLOC, stream);

    // final h is in hbuf[0] (step 511 writes buffer (512)&1 = 0, tag 0 = clean)
    classify_kernel<<<dim3(NCLS), dim3(256), 0, stream>>>(hbuf, Wc, bc, out);
}

// Round 6
// 1656.034 us; speedup vs baseline: 2.1436x; 1.5129x over previous
//
#include <hip/hip_runtime.h>

typedef _Float16 f16;
typedef _Float16 f16x8 __attribute__((ext_vector_type(8)));
typedef float f32x4 __attribute__((ext_vector_type(4)));
typedef float f32x16 __attribute__((ext_vector_type(16)));
typedef unsigned int u32;
typedef u32 u32x4 __attribute__((ext_vector_type(4)));

#define SEQ 512
#define BATCH 256
#define DIN 512
#define DH 1024
#define DK 1536
#define NCLS 1000

#define NGROUP 8      // groups == physical XCDs (dynamic via HW_REG_XCC_ID)
#define WGPG 32       // workgroups per group (1-WG/CU pigeonhole via 96KB LDS)
#define ROWS 32       // batch rows per group
#define OUTS 32       // hidden outputs per WG
#define KSLICES 96    // DK/16
#define RED_STRIDE 33

#define SMEM_ALLOC (96 * 1024)   // forces 1 WG/CU (occupancy), actual use ~50KB

// LDS offsets
#define XLDS_BYTES 32768                          // 32 frags x 1KB (f16 x-tile)
#define RED_OFF2   XLDS_BYTES
#define BLDS_OFF   (RED_OFF2 + 4 * OUTS * RED_STRIDE * 4)
#define META_OFF   (BLDS_OFF + OUTS * 4)

// ws layout
#define WF_BYTES   ((size_t)DH * DK * 2)          // 3 MB  W f16 frag layout
#define HP_OFF     WF_BYTES
#define HP_GROUP   (64 * 1024)                    // 64 frags x 1KB per group/buf
#define HP_HALF    ((size_t)NGROUP * HP_GROUP)    // 512 KB
#define HP_BYTES   (2 * HP_HALF)
#define SLOT_OFF   (HP_OFF + HP_BYTES)
#define SLOT_BYTES (NGROUP * 64)

// tag bit: f16 bit14. tanh output |h|<=1 -> bit14 always 0 in real data.
#define TAGBITS 0x40004000u
#define STRIPM  0xBFFFBFFFu

// ---- XCD-local L2-scope access: sc0 = bypass L1, coherence point = XCD L2 ----
__device__ __forceinline__ u32x4 hload4(const void* p) {
    u32x4 v;
    asm volatile("global_load_dwordx4 %0, %1, off sc0" : "=v"(v) : "v"(p) : "memory");
    return v;
}
__device__ __forceinline__ void hstore8(void* p, uint2 v) {
    asm volatile("global_store_dwordx2 %0, %1, off sc0" :: "v"(p), "v"(v) : "memory");
}

// ---- W [1024][1536] fp32 -> f16 A-fragment-linear layout ----
// Wf[((s*96 + j)*64 + lane)*8 + v] = W[s*32 + (lane&31)][j*16 + (lane>>5)*8 + v]
__global__ void __launch_bounds__(256) convert_W_kernel(const float* __restrict__ W,
                                                        f16* __restrict__ Wf) {
    int id = blockIdx.x * 256 + threadIdx.x;
    if (id >= DH * DK) return;
    int v = id & 7;
    int l = (id >> 3) & 63;
    int rest = id >> 9;            // s*96 + j
    int j = rest % KSLICES;
    int s = rest / KSLICES;
    int row = s * OUTS + (l & 31);
    int k = j * 16 + ((l >> 5) << 3) + v;
    Wf[id] = (f16)W[row * DK + k];
}

// ---- persistent RNN kernel: 256 WGs, grouped by physical XCD ----
// h exchange in MFMA-fragment-packed layout (fully coalesced), tagged data
// through the XCD-local L2 (sc0). x staged via LDS in fragment layout.
__global__ void __launch_bounds__(256, 1) rnn_kernel(const float* __restrict__ x,
                                                     const float* __restrict__ bias,
                                                     const f16* __restrict__ Wf,
                                                     f16* __restrict__ hpack,
                                                     int* __restrict__ xslots) {
    extern __shared__ char smem[];
    char*  xlds = smem;
    float* red  = (float*)(smem + RED_OFF2);
    float* blds = (float*)(smem + BLDS_OFF);
    int*   meta = (int*)(smem + META_OFF);

    const int tid  = threadIdx.x;
    const int wave = tid >> 6;
    const int lane = tid & 63;
    const int r    = lane & 31;        // batch row within group / MFMA B col
    const int hi   = lane >> 5;        // K-half within slice

    // ---- dynamic grouping: group = physical XCD, slot = arrival order ----
    if (tid == 0) {
        u32 xcc;
        asm volatile("s_getreg_b32 %0, hwreg(HW_REG_XCC_ID)" : "=s"(xcc));
        int g_ = (int)(xcc & 7);
        meta[0] = g_;
        meta[1] = atomicAdd(&xslots[g_], 1) & 31;
    }
    __syncthreads();
    const int g = meta[0];
    const int s = meta[1];

    if (tid < OUTS) blds[tid] = bias[s * OUTS + tid];

    // weight A-fragments -> registers (96 VGPRs/lane)
    f16x8 wf[24];
    {
        const f16x8* wp = ((const f16x8*)Wf) + (size_t)s * KSLICES * 64 + lane;
#pragma unroll
        for (int i = 0; i < 24; ++i) wf[i] = wp[(size_t)(wave + 4 * i) * 64];
    }

    // x-stage addressing: thread covers rows srow+4i, cols scol..scol+7
    const int srow = tid >> 6;
    const int scol = (tid & 63) * 8;
    const int sj   = scol >> 4;              // x fragment 0..31
    const int shi  = (scol >> 3) & 1;
    const int sswz = (sj & 7) << 4;

    // finish-phase assignment: thread = (batch row b_, 4-output chunk o0)
    const int b_ = tid >> 3;
    const int o0 = (tid & 7) * 4;
    const int fj  = (s << 1) + (o0 >> 4);    // packed h fragment j'
    const int fhi = (o0 >> 3) & 1;
    const size_t foff = (size_t)fj * 1024 + (((fhi << 5) + b_) * 16) + (o0 & 7) * 2;

    union cvt_t { u32x4 u; f16x8 h; };

    for (int t = 0; t < SEQ; ++t) {
        // ---- 1. stage x(t): coalesced f32 loads -> f16 -> swizzled LDS frags ----
        {
            const float* xt = x + ((size_t)t * BATCH + g * ROWS) * DIN;
#pragma unroll
            for (int i = 0; i < 8; ++i) {
                int row = srow + 4 * i;
                const float* xp = xt + row * DIN + scol;
                f32x4 a0 = *(const f32x4*)xp;
                f32x4 a1 = *(const f32x4*)(xp + 4);
                f16x8 o;
                o[0] = (f16)a0[0]; o[1] = (f16)a0[1]; o[2] = (f16)a0[2]; o[3] = (f16)a0[3];
                o[4] = (f16)a1[0]; o[5] = (f16)a1[1]; o[6] = (f16)a1[2]; o[7] = (f16)a1[3];
                int addr = (sj * 1024 + ((shi << 5) + row) * 16) ^ sswz;
                *(f16x8*)(xlds + addr) = o;
            }
        }
        __syncthreads();   // B1: xlds ready (also: all waves past finish(t-1))

        f32x16 accA = {0,0,0,0, 0,0,0,0, 0,0,0,0, 0,0,0,0};
        f32x16 accB = {0,0,0,0, 0,0,0,0, 0,0,0,0, 0,0,0,0};

        // ---- 2. x-MFMA from LDS (pre-poll; overlaps producer tails) ----
#pragma unroll
        for (int i = 0; i < 8; ++i) {
            int j = wave + 4 * i;
            f16x8 bf = *(const f16x8*)(xlds + ((j * 1024 + lane * 16) ^ ((j & 7) << 4)));
            if (i & 1) accB = __builtin_amdgcn_mfma_f32_32x32x16_f16(wf[i], bf, accB, 0, 0, 0);
            else       accA = __builtin_amdgcn_mfma_f32_32x32x16_f16(wf[i], bf, accA, 0, 0, 0);
        }

        // ---- 3. h-part: poll packed tagged fragments, 2 halves of 8 ----
        {
            const char* hpb = (const char*)hpack
                            + ((size_t)((t & 1) * NGROUP + g)) * HP_GROUP
                            + wave * 1024 + lane * 16;
            const u32 rtag = (u32)((t >> 1) & 1);
#pragma unroll
            for (int hh = 0; hh < 2; ++hh) {
                const char* pb = hpb + hh * 32768;
                u32x4 hv[8];
                if (rtag == 0) {
                    for (;;) {
#pragma unroll
                        for (int q = 0; q < 8; ++q) hv[q] = hload4(pb + q * 4096);
                        asm volatile("s_waitcnt vmcnt(0)" ::: "memory");
                        __builtin_amdgcn_sched_barrier(0);
                        u32 orr = 0;
#pragma unroll
                        for (int q = 0; q < 8; ++q) orr |= hv[q].x | hv[q].y | hv[q].z | hv[q].w;
                        if (__all((orr & TAGBITS) == 0u)) break;
                    }
                } else {
                    for (;;) {
#pragma unroll
                        for (int q = 0; q < 8; ++q) hv[q] = hload4(pb + q * 4096);
                        asm volatile("s_waitcnt vmcnt(0)" ::: "memory");
                        __builtin_amdgcn_sched_barrier(0);
                        u32 andv = 0xFFFFFFFFu;
#pragma unroll
                        for (int q = 0; q < 8; ++q) andv &= hv[q].x & hv[q].y & hv[q].z & hv[q].w;
                        if (__all((andv & TAGBITS) == TAGBITS)) break;
                    }
#pragma unroll
                    for (int q = 0; q < 8; ++q) hv[q] &= STRIPM;
                }
                __builtin_amdgcn_sched_barrier(0);
#pragma unroll
                for (int q = 0; q < 8; ++q) {
                    cvt_t c; c.u = hv[q];
                    if (q & 1) accB = __builtin_amdgcn_mfma_f32_32x32x16_f16(wf[8 + 8 * hh + q], c.h, accB, 0, 0, 0);
                    else       accA = __builtin_amdgcn_mfma_f32_32x32x16_f16(wf[8 + 8 * hh + q], c.h, accA, 0, 0, 0);
                }
            }
        }

        // ---- 4. K-split partials -> LDS (C/D: col=lane&31, row=(v&3)+8*(v>>2)+4*hi) ----
        {
            float* rw = red + wave * (OUTS * RED_STRIDE);
            int rbase = hi << 2;
#pragma unroll
            for (int v = 0; v < 16; ++v) {
                int orow = (v & 3) + 8 * (v >> 2) + rbase;
                rw[orow * RED_STRIDE + r] = accA[v] + accB[v];
            }
        }
        __syncthreads();   // B2: red ready

        // ---- 5. finish: reduce 4 partials + bias, fast tanh, packed tagged store ----
        {
            const u32 wtag = (u32)(((t + 1) >> 1) & 1);
            char* hob = (char*)hpack
                      + ((size_t)(((t + 1) & 1) * NGROUP + g)) * HP_GROUP + foff;
            union { f16 h4[4]; uint2 u; } uu;
#pragma unroll
            for (int i = 0; i < 4; ++i) {
                int o = o0 + i;
                float p = blds[o];
#pragma unroll
                for (int w2 = 0; w2 < 4; ++w2)
                    p += red[w2 * (OUTS * RED_STRIDE) + o * RED_STRIDE + b_];
                // tanh(p) = 1 - 2/(e^{2p}+1); |result| <= 1 so f16 bit14 == 0
                float e = __expf(2.f * p);
                uu.h4[i] = (f16)(1.f - 2.f / (e + 1.f));
            }
            if (wtag) { uu.u.x |= TAGBITS; uu.u.y |= TAGBITS; }
            hstore8(hob, uu.u);
        }
        // no barrier here: B1 of next iter orders finish(t) before red/xlds reuse
    }
}

// ---- classify: block per class, thread per batch row (reads packed buf 0) ----
__global__ void __launch_bounds__(256) classify_kernel(const f16* __restrict__ hpack,
                                                       const float* __restrict__ Wc,
                                                       const float* __restrict__ bc,
                                                       float* __restrict__ out) {
    __shared__ float wrow[DH];
    int c = blockIdx.x;
    int tid = threadIdx.x;
    for (int i = tid; i < DH; i += 256) wrow[i] = Wc[(size_t)c * DH + i];
    __syncthreads();
    int g = tid >> 5, r2 = tid & 31;
    const char* base = (const char*)hpack + (size_t)g * HP_GROUP;   // buffer 0
    float acc = bc[c];
    for (int j = 0; j < 64; ++j) {
#pragma unroll
        for (int h2 = 0; h2 < 2; ++h2) {
            f16x8 hv = *(const f16x8*)(base + j * 1024 + ((h2 << 5) + r2) * 16);
            int k = j * 16 + h2 * 8;
#pragma unroll
            for (int v = 0; v < 8; ++v) acc += (float)hv[v] * wrow[k + v];
        }
    }
    out[(size_t)tid * NCLS + c] = acc;
}

extern "C" void kernel_launch(void* const* d_in, const int* in_sizes, int n_in,
                              void* d_out, int out_size, void* d_ws, size_t ws_size,
                              hipStream_t stream) {
    const float* x  = (const float*)d_in[0];
    const float* W  = (const float*)d_in[1];
    const float* b  = (const float*)d_in[2];
    const float* Wc = (const float*)d_in[3];
    const float* bc = (const float*)d_in[4];
    float* out = (float*)d_out;

    char* ws = (char*)d_ws;
    f16* Wf     = (f16*)ws;
    f16* hpack  = (f16*)(ws + HP_OFF);
    int* xslots = (int*)(ws + SLOT_OFF);

    // buffer 0: zeros = h0 (valid, tag 0).  buffer 1: 0x4040 = stale (bit14 set)
    // for the first tag-0 read at t=1.  Slot counters zeroed.  Every call.
    hipMemsetAsync(hpack, 0, HP_HALF, stream);
    hipMemsetAsync((char*)hpack + HP_HALF, 0x40, HP_HALF, stream);
    hipMemsetAsync(xslots, 0, SLOT_BYTES, stream);

    convert_W_kernel<<<(DH * DK + 255) / 256, 256, 0, stream>>>(W, Wf);

    hipFuncSetAttribute((const void*)rnn_kernel,
                        hipFuncAttributeMaxDynamicSharedMemorySize, SMEM_ALLOC);
    void* args[5];
    args[0] = (void*)&x;
    args[1] = (void*)&b;
    args[2] = (void*)&Wf;
    args[3] = (void*)&hpack;
    args[4] = (void*)&xslots;
    hipLaunchCooperativeKernel((const void*)rnn_kernel, dim3(256), dim3(256),
                               args, SMEM_ALLOC, stream);

    // final h is in packed buffer 0 (step 511 writes buf (512)&1=0, tag 0 clean)
    classify_kernel<<<dim3(NCLS), dim3(256), 0, stream>>>(hpack, Wc, bc, out);
}

// Round 8
// 1240.619 us; speedup vs baseline: 2.8614x; 1.3348x over previous
//
#include <hip/hip_runtime.h>

typedef _Float16 f16;
typedef _Float16 f16x8 __attribute__((ext_vector_type(8)));
typedef float f32x4 __attribute__((ext_vector_type(4)));
typedef float f32x16 __attribute__((ext_vector_type(16)));
typedef unsigned int u32;
typedef u32 u32x4 __attribute__((ext_vector_type(4)));

#define SEQ 512
#define BATCH 256
#define DIN 512
#define DH 1024
#define DK 1536
#define NCLS 1000

#define NGROUP 8      // groups == physical XCDs (dynamic via HW_REG_XCC_ID)
#define ROWS 32
#define OUTS 32
#define KSLICES 96
#define RED_STRIDE 33

#define SMEM_ALLOC (96 * 1024)   // pigeonhole: 1 WG/CU -> 32 WGs per XCD

// LDS map: two 32KB x-frag buffers | red | blds | meta
#define XLDS1_OFF 32768
#define RED_OFF3  65536
#define RED_BYTES (4 * OUTS * RED_STRIDE * 4)
#define BLDS_OFF  (RED_OFF3 + RED_BYTES)
#define META_OFF  (BLDS_OFF + OUTS * 4)

// ws map
#define WF_OFF     0
#define HP_OFF     ((size_t)4 << 20)
#define HP_GROUP   65536                            // 64 frags x 1KB
#define HP_HALF    ((size_t)NGROUP * HP_GROUP)      // 512 KB
#define HP_BYTES   (2 * HP_HALF)
#define SLOT_OFF   ((size_t)6 << 20)
#define SLOT_BYTES (NGROUP * 64)
#define XF_OFF     ((size_t)8 << 20)
#define XF_BYTES   ((size_t)SEQ * NGROUP * 32 * 1024)   // 128 MB
#define WS_NEED    (XF_OFF + XF_BYTES)

// tag bit: f16 bit14. tanh output |h|<=1 -> bit14 always 0 in real data.
#define TAGBITS 0x40004000u
#define STRIPM  0xBFFFBFFFu

// ---- XCD-local L2-scope access (sc0 = bypass L1; group lives on one XCD) ----
__device__ __forceinline__ u32x4 hload4(const void* p) {
    u32x4 v;
    asm volatile("global_load_dwordx4 %0, %1, off sc0" : "=v"(v) : "v"(p) : "memory");
    return v;
}
__device__ __forceinline__ void hstore8(void* p, uint2 v) {
    asm volatile("global_store_dwordx2 %0, %1, off sc0" :: "v"(p), "v"(v) : "memory");
}
// async global->LDS, 16B per lane; LDS dest = wave-uniform base + lane*16
__device__ __forceinline__ void glds16(const void* gsrc, void* ldst) {
    __builtin_amdgcn_global_load_lds(
        (const __attribute__((address_space(1))) u32*)gsrc,
        (__attribute__((address_space(3))) u32*)ldst, 16, 0, 0);
}
__device__ __forceinline__ void barrier_lgkm_only() {
    __builtin_amdgcn_sched_barrier(0);
    asm volatile("s_waitcnt lgkmcnt(0)" ::: "memory");
    __builtin_amdgcn_s_barrier();
    asm volatile("" ::: "memory");
    __builtin_amdgcn_sched_barrier(0);
}

// ---- W [1024][1536] fp32 -> f16 A-fragment-linear layout ----
// Wf[((s*96 + j)*64 + lane)*8 + v] = W[s*32 + (lane&31)][j*16 + (lane>>5)*8 + v]
__global__ void __launch_bounds__(256) convert_W_kernel(const float* __restrict__ W,
                                                        f16* __restrict__ Wf) {
    int id = blockIdx.x * 256 + threadIdx.x;
    if (id >= DH * DK) return;
    int v = id & 7;
    int l = (id >> 3) & 63;
    int rest = id >> 9;
    int j = rest % KSLICES;
    int s = rest / KSLICES;
    int row = s * OUTS + (l & 31);
    int k = j * 16 + ((l >> 5) << 3) + v;
    Wf[id] = (f16)W[row * DK + k];
}

// ---- x [SEQ][BATCH][DIN] f32 -> fragment-packed f16 xf[t][g][j][lane][16B] ----
__global__ void __launch_bounds__(256) convert_x_kernel(const float* __restrict__ x,
                                                        f16* __restrict__ xf) {
    __shared__ f16 tile[ROWS * DIN];   // 32 KB
    const int tid = threadIdx.x;
    const float* src = x + (size_t)blockIdx.x * (ROWS * DIN);  // blockIdx = t*8+g
#pragma unroll
    for (int c = 0; c < 16; ++c) {
        int off = (c * 256 + tid) * 4;
        f32x4 a = *(const f32x4*)(src + off);
        union { f16 h[4]; uint2 u; } uu;
        uu.h[0] = (f16)a[0]; uu.h[1] = (f16)a[1]; uu.h[2] = (f16)a[2]; uu.h[3] = (f16)a[3];
        *(uint2*)&tile[off] = uu.u;
    }
    __syncthreads();
    char* dst = (char*)xf + (size_t)blockIdx.x * 32768 + tid * 128;
    int j = tid >> 3;
    int l0 = (tid & 7) * 8;
    f16x8 buf[8];
#pragma unroll
    for (int e = 0; e < 8; ++e) {
        int l = l0 + e;
        buf[e] = *(const f16x8*)&tile[(l & 31) * DIN + j * 16 + (l >> 5) * 8];
    }
#pragma unroll
    for (int e = 0; e < 8; ++e) *(f16x8*)(dst + e * 16) = buf[e];
}

// ---- persistent RNN kernel: 256 WGs, grouped by physical XCD ----
// XF=true : x pre-packed f16 frags staged via global_load_lds, double-buffered.
// XF=false: R6 fallback — f32 x staged via regs->swizzled LDS each step.
// h exchange: tag-in-data (bit14 generation tags) through XCD-local L2.
template<bool XF>
__global__ void __launch_bounds__(256, 1)
rnn_kernel(const float* __restrict__ x, const float* __restrict__ bias,
           const f16* __restrict__ Wf, const f16* __restrict__ xf,
           f16* __restrict__ hpack, int* __restrict__ xslots) {
    extern __shared__ char smem[];
    char*  xlds = smem;
    float* red  = (float*)(smem + RED_OFF3);
    float* blds = (float*)(smem + BLDS_OFF);
    int*   meta = (int*)(smem + META_OFF);

    const int tid  = threadIdx.x;
    const int wave = tid >> 6;
    const int lane = tid & 63;
    const int r    = lane & 31;
    const int hi   = lane >> 5;

    if (tid == 0) {
        u32 xcc;
        asm volatile("s_getreg_b32 %0, hwreg(HW_REG_XCC_ID)" : "=s"(xcc));
        meta[0] = (int)(xcc & 7);
        meta[1] = atomicAdd(&xslots[xcc & 7], 1) & 31;
    }
    __syncthreads();
    const int g = meta[0];
    const int s = meta[1];
    if (tid < OUTS) blds[tid] = bias[s * OUTS + tid];

    // weight A-fragments -> registers (96 VGPRs/lane)
    f16x8 wf[24];
    {
        const f16x8* wp = ((const f16x8*)Wf) + (size_t)s * KSLICES * 64 + lane;
#pragma unroll
        for (int i = 0; i < 24; ++i) wf[i] = wp[(size_t)(wave + 4 * i) * 64];
    }

    // finish-phase assignment
    const int b_ = tid >> 3, o0 = (tid & 7) * 4;
    const int fj = (s << 1) + (o0 >> 4);
    const size_t foff = (size_t)fj * 1024 + ((((o0 >> 3) & 1) << 5) + b_) * 16 + (o0 & 7) * 2;

    // fallback staging vars (R6)
    const int srow = tid >> 6, scol = (tid & 63) * 8;
    const int sj = scol >> 4, shi = (scol >> 3) & 1, sswz = (sj & 7) << 4;

    union cvt_t { u32x4 u; f16x8 h; };

    // ---- prologue (XF): stage x(0) into xlds buf0 via global_load_lds ----
    if constexpr (XF) {
        const char* xg = (const char*)xf + (size_t)g * 32768 + lane * 16;
#pragma unroll
        for (int i = 0; i < 8; ++i) {
            int j = wave + 4 * i;
            glds16(xg + j * 1024, xlds + j * 1024);
        }
        asm volatile("s_waitcnt vmcnt(0)" ::: "memory");
        __syncthreads();
    }

    for (int t = 0; t < SEQ; ++t) {
        // ---- 0. (fallback) stage x(t): f32 -> f16 -> swizzled LDS ----
        if constexpr (!XF) {
            const float* xt = x + ((size_t)t * BATCH + g * ROWS) * DIN;
#pragma unroll
            for (int i = 0; i < 8; ++i) {
                int row = srow + 4 * i;
                const float* xp = xt + row * DIN + scol;
                f32x4 a0 = *(const f32x4*)xp;
                f32x4 a1 = *(const f32x4*)(xp + 4);
                f16x8 o;
                o[0] = (f16)a0[0]; o[1] = (f16)a0[1]; o[2] = (f16)a0[2]; o[3] = (f16)a0[3];
                o[4] = (f16)a1[0]; o[5] = (f16)a1[1]; o[6] = (f16)a1[2]; o[7] = (f16)a1[3];
                *(f16x8*)(xlds + ((sj * 1024 + ((shi << 5) + row) * 16) ^ sswz)) = o;
            }
            __syncthreads();
        }

        f32x16 accA = {0,0,0,0, 0,0,0,0, 0,0,0,0, 0,0,0,0};
        f32x16 accB = {0,0,0,0, 0,0,0,0, 0,0,0,0, 0,0,0,0};

        // ---- 1. x-MFMA from LDS ----
        {
            const char* xc = xlds + (XF ? (t & 1) * XLDS1_OFF : 0);
#pragma unroll
            for (int i = 0; i < 8; ++i) {
                int j = wave + 4 * i;
                f16x8 bf;
                if constexpr (XF)
                    bf = *(const f16x8*)(xc + j * 1024 + lane * 16);
                else
                    bf = *(const f16x8*)(xc + ((j * 1024 + lane * 16) ^ ((j & 7) << 4)));
                if (i & 1) accB = __builtin_amdgcn_mfma_f32_32x32x16_f16(wf[i], bf, accB, 0, 0, 0);
                else       accA = __builtin_amdgcn_mfma_f32_32x32x16_f16(wf[i], bf, accA, 0, 0, 0);
            }
        }

        // ---- 2. (XF) async-prefetch x(t+1) into the other LDS buffer ----
        if constexpr (XF) {
            int tn = t + 1; if (tn == SEQ) tn = SEQ - 1;
            const char* xg = (const char*)xf + (size_t)(tn * NGROUP + g) * 32768 + lane * 16;
            char* xn = xlds + ((t + 1) & 1) * XLDS1_OFF;
#pragma unroll
            for (int i = 0; i < 8; ++i) {
                int j = wave + 4 * i;
                glds16(xg + j * 1024, xn + j * 1024);
            }
        }

        // ---- 3. h-part: poll the tagged data itself (validated R6 protocol) ----
        {
            const char* hpb = (const char*)hpack + (size_t)((t & 1) * NGROUP + g) * HP_GROUP
                            + wave * 1024 + lane * 16;
            const u32 rtag = (u32)((t >> 1) & 1);
#pragma unroll
            for (int hh = 0; hh < 2; ++hh) {
                const char* pb = hpb + hh * 32768;
                u32x4 hv[8];
                if (rtag == 0) {
                    for (;;) {
#pragma unroll
                        for (int q = 0; q < 8; ++q) hv[q] = hload4(pb + q * 4096);
                        asm volatile("s_waitcnt vmcnt(0)" ::: "memory");
                        __builtin_amdgcn_sched_barrier(0);
                        u32 orr = 0;
#pragma unroll
                        for (int q = 0; q < 8; ++q) orr |= hv[q].x | hv[q].y | hv[q].z | hv[q].w;
                        if (__all((orr & TAGBITS) == 0u)) break;
                    }
                } else {
                    for (;;) {
#pragma unroll
                        for (int q = 0; q < 8; ++q) hv[q] = hload4(pb + q * 4096);
                        asm volatile("s_waitcnt vmcnt(0)" ::: "memory");
                        __builtin_amdgcn_sched_barrier(0);
                        u32 andv = 0xFFFFFFFFu;
#pragma unroll
                        for (int q = 0; q < 8; ++q) andv &= hv[q].x & hv[q].y & hv[q].z & hv[q].w;
                        if (__all((andv & TAGBITS) == TAGBITS)) break;
                    }
#pragma unroll
                    for (int q = 0; q < 8; ++q) hv[q] &= STRIPM;
                }
                __builtin_amdgcn_sched_barrier(0);
#pragma unroll
                for (int q = 0; q < 8; ++q) {
                    cvt_t c; c.u = hv[q];
                    if (q & 1) accB = __builtin_amdgcn_mfma_f32_32x32x16_f16(wf[8 + 8 * hh + q], c.h, accB, 0, 0, 0);
                    else       accA = __builtin_amdgcn_mfma_f32_32x32x16_f16(wf[8 + 8 * hh + q], c.h, accA, 0, 0, 0);
                }
            }
        }

        // ---- 4. K-split partials -> LDS ----
        {
            float* rw = red + wave * (OUTS * RED_STRIDE);
            int rb = hi << 2;
#pragma unroll
            for (int v = 0; v < 16; ++v) {
                int orow = (v & 3) + 8 * (v >> 2) + rb;
                rw[orow * RED_STRIDE + r] = accA[v] + accB[v];
            }
        }
        if constexpr (XF) barrier_lgkm_only();
        else              __syncthreads();

        // ---- 5. finish: reduce 4 partials + bias, fast tanh, tagged store ----
        {
            const u32 wtag = (u32)(((t + 1) >> 1) & 1);
            char* hob = (char*)hpack + (size_t)(((t + 1) & 1) * NGROUP + g) * HP_GROUP + foff;
            union { f16 h4[4]; uint2 u; } uu;
#pragma unroll
            for (int i = 0; i < 4; ++i) {
                int o = o0 + i;
                float p = blds[o];
#pragma unroll
                for (int w2 = 0; w2 < 4; ++w2)
                    p += red[w2 * (OUTS * RED_STRIDE) + o * RED_STRIDE + b_];
                // tanh(p) = 1 - 2/(e^{2p}+1); |result| <= 1 so f16 bit14 == 0
                float e = __expf(2.f * p);
                uu.h4[i] = (f16)(1.f - 2.f / (e + 1.f));
            }
            if (wtag) { uu.u.x |= TAGBITS; uu.u.y |= TAGBITS; }
            hstore8(hob, uu.u);
        }
        // end-of-step barrier: protects red[] WAR and (XF) xlds buffer swap.
        // Tags make vmcnt-draining unnecessary; fallback keeps R6's ordering
        // via the stage-phase __syncthreads at the top of the next iteration.
        if constexpr (XF) barrier_lgkm_only();
    }
}

// ---- classify: block per class, thread per batch row (packed buf 0) ----
__global__ void __launch_bounds__(256) classify_kernel(const f16* __restrict__ hpack,
                                                       const float* __restrict__ Wc,
                                                       const float* __restrict__ bc,
                                                       float* __restrict__ out) {
    __shared__ float wrow[DH];
    int c = blockIdx.x;
    int tid = threadIdx.x;
    for (int i = tid; i < DH; i += 256) wrow[i] = Wc[(size_t)c * DH + i];
    __syncthreads();
    int g = tid >> 5, r2 = tid & 31;
    const char* base = (const char*)hpack + (size_t)g * HP_GROUP;   // buffer 0
    float acc = bc[c];
    for (int j = 0; j < 64; ++j) {
#pragma unroll
        for (int h2 = 0; h2 < 2; ++h2) {
            f16x8 hv = *(const f16x8*)(base + j * 1024 + ((h2 << 5) + r2) * 16);
            int k = j * 16 + h2 * 8;
#pragma unroll
            for (int v = 0; v < 8; ++v) acc += (float)hv[v] * wrow[k + v];
        }
    }
    out[(size_t)tid * NCLS + c] = acc;
}

extern "C" void kernel_launch(void* const* d_in, const int* in_sizes, int n_in,
                              void* d_out, int out_size, void* d_ws, size_t ws_size,
                              hipStream_t stream) {
    const float* x  = (const float*)d_in[0];
    const float* W  = (const float*)d_in[1];
    const float* b  = (const float*)d_in[2];
    const float* Wc = (const float*)d_in[3];
    const float* bc = (const float*)d_in[4];
    float* out = (float*)d_out;

    char* ws = (char*)d_ws;
    f16* Wf     = (f16*)(ws + WF_OFF);
    f16* hpack  = (f16*)(ws + HP_OFF);
    int* xslots = (int*)(ws + SLOT_OFF);
    f16* xf     = (f16*)(ws + XF_OFF);

    const bool bigws = (ws_size >= WS_NEED);

    // buffer 0: zeros = h0 (valid, tag 0).  buffer 1: 0x4040 = stale (bit14
    // set) for the first tag-0 read at t=1.  Slot counters zeroed.  Every call.
    hipMemsetAsync(hpack, 0, HP_HALF, stream);
    hipMemsetAsync((char*)hpack + HP_HALF, 0x40, HP_HALF, stream);
    hipMemsetAsync(xslots, 0, SLOT_BYTES, stream);

    convert_W_kernel<<<(DH * DK + 255) / 256, 256, 0, stream>>>(W, Wf);
    if (bigws)
        convert_x_kernel<<<dim3(SEQ * NGROUP), dim3(256), 0, stream>>>(x, xf);

    const void* kfn = bigws ? (const void*)rnn_kernel<true>
                            : (const void*)rnn_kernel<false>;
    hipFuncSetAttribute(kfn, hipFuncAttributeMaxDynamicSharedMemorySize, SMEM_ALLOC);
    void* args[6];
    args[0] = (void*)&x;
    args[1] = (void*)&b;
    args[2] = (void*)&Wf;
    args[3] = (void*)&xf;
    args[4] = (void*)&hpack;
    args[5] = (void*)&xslots;
    hipLaunchCooperativeKernel(kfn, dim3(256), dim3(256), args, SMEM_ALLOC, stream);

    // final h in packed buffer 0 (step 511 writes buf (512)&1 = 0, tag 0 clean)
    classify_kernel<<<dim3(NCLS), dim3(256), 0, stream>>>(hpack, Wc, bc, out);
}